// Round 9
// baseline (78.958 us; speedup 1.0000x reference)
//
#include <hip/hip_runtime.h>
#include <math.h>
#include <stdint.h>

#define RB 256      // block size
#define KB 256      // rank blocks (n / IK)
#define IK 32       // i-keys owned per rank block
#define JS 32       // j-iterations per thread in rank phase (n / RB)
#define GM 1024     // Gauss-transform grid points
#define YS 128      // gt source-splits (R2-proven geometry)
#define FB 32       // final blocks (n / RB)

#define SCALE 0.84932180028801904f   // 1/sqrt(2 ln2): exp(-d^2/2) = exp2(-(SCALE*d)^2)
#define SQRT2PI 2.5066282746310002f
#define KFP 0.46971863934f           // 1/(SCALE*sqrt(2pi)) : dPhiSum/dx = KFP*A
#define LN2 0.69314718056f

__device__ __forceinline__ uint64_t order_key(float f, int idx) {
  unsigned u = __float_as_uint(f);
  u = (u & 0x80000000u) ? ~u : (u | 0x80000000u);
  return ((uint64_t)u << 32) | (unsigned)idx;
}

__device__ __forceinline__ float e_of(const float* theta, const float* dur, int i) {
  return logf(dur[i] + 1e-32f) - theta[i];   // deterministic: identical everywhere
}

// grid geometry from the sorted endpoints (identical fp ops in every consumer)
__device__ __forceinline__ void grid_geom(const float2* xe, int n, float* x0, float* hx) {
  float a = xe[0].x - 7.0f;        // ~8 sigma margin in prescaled units
  float b = xe[n - 1].x + 7.0f;
  *x0 = a;
  *hx = (b - a) / (float)(GM - 1);
}

// ---------------------------------------------------------------------------
// Kernel 0: materialize sort keys ONCE (kills the 2.1M redundant logf in the
// rank loop: 256 blocks x 8192 j-keys -> 8192 total). 32 blocks. Side duties:
// blocks 0..15 zero gbuf (4*GM floats), block 16 zeroes out[0].
// ---------------------------------------------------------------------------
__global__ __launch_bounds__(RB) void keys_kernel(
    const float* __restrict__ theta, const float* __restrict__ dur,
    uint64_t* __restrict__ keys, float* __restrict__ gbuf,
    float* __restrict__ out, int n) {
  const int i = blockIdx.x * RB + threadIdx.x;
  keys[i] = order_key(e_of(theta, dur, i), i);
  if (blockIdx.x < 16) gbuf[blockIdx.x * RB + threadIdx.x] = 0.0f;  // 16*256=4*GM
  if (i == 16 * RB) out[0] = 0.0f;
}

// ---------------------------------------------------------------------------
// Kernel 1: full rank + scatter in ONE dispatch. Block b holds i-keys
// [32b,32b+32) in registers (via LDS broadcast); each thread streams a
// COALESCED 32-element j-stripe of the precomputed key array (8 B/lane
// global_load_dwordx2, 64 KB buffer = L2-resident; unlike R1's block-uniform
// reads which wasted a 512 B transaction per key) and compares against all 32
// i-keys in registers. shfl + LDS reduce -> complete ranks -> scatter:
//   xe[r].x = SCALE*e(k); xe[k].y = ev[r]; th_s[k] = theta[r]
// ---------------------------------------------------------------------------
__global__ __launch_bounds__(RB) void rank_scatter_kernel(
    const float* __restrict__ theta, const float* __restrict__ dur,
    const int* __restrict__ ev, const uint64_t* __restrict__ keys,
    float2* __restrict__ xe, float* __restrict__ th_s, int n) {
  __shared__ uint64_t kt[IK];
  __shared__ int part[4 * IK];
  const int tid = threadIdx.x, bid = blockIdx.x;
  const int k0 = bid * IK;

  if (tid < IK) kt[tid] = keys[k0 + tid];
  __syncthreads();

  uint64_t ki[IK];
  int cnt[IK];
  #pragma unroll
  for (int p = 0; p < IK; ++p) { ki[p] = kt[p]; cnt[p] = 0; }

  #pragma unroll 4
  for (int s = 0; s < JS; ++s) {
    uint64_t jk = keys[s * RB + tid];                // coalesced stripe, L2-hit
    #pragma unroll
    for (int p = 0; p < IK; ++p) cnt[p] += (jk < ki[p]) ? 1 : 0;
  }

  // reduce each of the 32 counts across the 64-lane wave, then across waves
  #pragma unroll
  for (int p = 0; p < IK; ++p) {
    #pragma unroll
    for (int off = 32; off > 0; off >>= 1) cnt[p] += __shfl_down(cnt[p], off, 64);
  }
  int wave = tid >> 6, lane = tid & 63;
  if (lane == 0) {
    #pragma unroll
    for (int p = 0; p < IK; ++p) part[wave * IK + p] = cnt[p];
  }
  __syncthreads();

  if (tid < IK) {
    int r = part[tid] + part[IK + tid] + part[2 * IK + tid] + part[3 * IK + tid];
    int k = k0 + tid;
    ((float*)&xe[r])[0] = SCALE * e_of(theta, dur, k);   // scatter (distinct dword)
    ((float*)&xe[k])[1] = (float)ev[r];                  // inverse-perm side reorder
    th_s[k] = theta[r];
  }
}

// ---------------------------------------------------------------------------
// Kernel 2: Gauss transform on the grid (R2-proven verbatim, ~2.5 us incl.
// atomics: 524K RMWs SPREAD over 4096 distinct addresses pipeline fine at the
// coherent point -- unlike same-line chains). dp = x_m - x_j (prescaled).
//   A = sum g; B = sum ev*g; F = sum Phi(d); D = sum dp*ev*g
// ---------------------------------------------------------------------------
__global__ __launch_bounds__(RB) void gt_kernel(
    const float2* __restrict__ xe, float* __restrict__ gbuf, int n) {
  float x0, hx;
  grid_geom(xe, n, &x0, &hx);
  int m = blockIdx.x * RB + threadIdx.x;        // gridDim.x = GM/RB = 4
  float xm = fmaf((float)m, hx, x0);
  const int chunk = n / YS;                      // 64
  int jb = blockIdx.y * chunk;
  const float P2S = 0.39169197f;   // 0.47047*sqrt(ln2): t = 1/(1+p|d|/sqrt2)
  float a = 0.0f, b = 0.0f, f = 0.0f, d = 0.0f;
  #pragma unroll 8
  for (int jj = 0; jj < chunk; ++jj) {
    float2 q = xe[jb + jj];                      // block-uniform address
    float dp = xm - q.x;
    float g = __builtin_amdgcn_exp2f(-(dp * dp));  // exp(-d^2/2)
    float evg = q.y * g;
    a += g;
    b += evg;
    d = fmaf(dp, evg, d);
    // A&S 7.1.25 erf (p=0.47047, |err|<=2.5e-5), reuses g
    float tt = __builtin_amdgcn_rcpf(fmaf(P2S, __builtin_fabsf(dp), 1.0f));
    float poly = tt * (0.3480242f + tt * (-0.0958798f + tt * 0.7478556f));
    f += __builtin_copysignf(fmaf(-poly, g, 1.0f), dp);   // sign*erf
  }
  atomicAdd(&gbuf[m], a);
  atomicAdd(&gbuf[GM + m], b);
  atomicAdd(&gbuf[2 * GM + m], 0.5f * (float)chunk + 0.5f * f);  // Phi = .5+.5*s
  atomicAdd(&gbuf[3 * GM + m], d);
}

// ---------------------------------------------------------------------------
// Kernel 3: per-element cubic Hermite interpolation of FPhi (cdf-sum) and B
// (pdf*ev sum), then the loss terms (R2-proven verbatim, ~1.5 us). gbuf is
// only 16 KB -- served from IF/L2 to all 32 blocks. One atomic per block.
// ---------------------------------------------------------------------------
__global__ __launch_bounds__(RB) void final_kernel(
    const float2* __restrict__ xe, const float* __restrict__ th_s,
    const float* __restrict__ gbuf, float* __restrict__ out, int n) {
  float x0, hx;
  grid_geom(xe, n, &x0, &hx);
  const float* A = gbuf;
  const float* B = gbuf + GM;
  const float* F = gbuf + 2 * GM;
  const float* D = gbuf + 3 * GM;
  int i = blockIdx.x * RB + threadIdx.x;

  float term = 0.0f;
  if (i < n) {
    float2 q = xe[i];
    float u = (q.x - x0) * __builtin_amdgcn_rcpf(hx);
    int m = (int)u;
    m = min(max(m, 0), GM - 2);
    float t = u - (float)m;
    t = fminf(fmaxf(t, 0.0f), 1.0f);
    float t2 = t * t, t3 = t2 * t;
    float h00 = 2.0f * t3 - 3.0f * t2 + 1.0f;
    float h01 = 3.0f * t2 - 2.0f * t3;
    float h10 = t3 - 2.0f * t2 + t;
    float h11 = t3 - t2;
    float Fi = F[m] * h00 + F[m + 1] * h01 +
               hx * KFP * (A[m] * h10 + A[m + 1] * h11);
    float Bi = B[m] * h00 + B[m + 1] * h01 -
               2.0f * LN2 * hx * (D[m] * h10 + D[m + 1] * h11);
    const float fn = (float)n;
    float condE = fmaxf(Bi, 0.0f) * (1.0f / SQRT2PI) / fn + fn * 1e-32f;
    float surv = fmaxf(Fi, 0.25f) / fn;    // exact math gives Fi >= 0.5
    term = (__logf(condE) - __logf(surv) + th_s[i]) * q.y;
  }

  #pragma unroll
  for (int off = 32; off > 0; off >>= 1) term += __shfl_down(term, off, 64);
  __shared__ float red[RB / 64];
  int wave = threadIdx.x >> 6, lane = threadIdx.x & 63;
  if (lane == 0) red[wave] = term;
  __syncthreads();
  if (threadIdx.x == 0) {
    float s = 0.0f;
    #pragma unroll
    for (int w = 0; w < RB / 64; ++w) s += red[w];
    atomicAdd(out, -s / (float)n);
  }
}

extern "C" void kernel_launch(void* const* d_in, const int* in_sizes, int n_in,
                              void* d_out, int out_size, void* d_ws, size_t ws_size,
                              hipStream_t stream) {
  const float* theta = (const float*)d_in[0];   // log_h (n,1) fp32
  const float* dur   = (const float*)d_in[1];   // durations (n,) fp32
  const int*   ev    = (const int*)d_in[2];     // events (n,) int32
  float* out = (float*)d_out;
  int n = in_sizes[1];

  // workspace layout (8-byte aligned first)
  char* ws = (char*)d_ws;
  float2*   xe   = (float2*)ws;    ws += n * sizeof(float2);
  uint64_t* keys = (uint64_t*)ws;  ws += n * sizeof(uint64_t);
  float*    th_s = (float*)ws;     ws += n * sizeof(float);
  float*    gbuf = (float*)ws;     ws += 4 * GM * sizeof(float);  // A|B|F|D

  keys_kernel<<<n / RB, RB, 0, stream>>>(theta, dur, keys, gbuf, out, n);
  rank_scatter_kernel<<<KB, RB, 0, stream>>>(theta, dur, ev, keys, xe, th_s, n);
  gt_kernel<<<dim3(GM / RB, YS), RB, 0, stream>>>(xe, gbuf, n);
  final_kernel<<<FB, RB, 0, stream>>>(xe, th_s, gbuf, out, n);
}

// Round 10
// 75.368 us; speedup vs baseline: 1.0476x; 1.0476x over previous
//
#include <hip/hip_runtime.h>
#include <math.h>
#include <stdint.h>

#define RB 256      // block size
#define JT 256      // j-tile (keys) per block in rank phase
#define IPT 2       // i-keys per thread in rank phase
#define GM 1024     // Gauss-transform grid points
#define YS 128      // source-splits in gt phase

#define SCALE 0.84932180028801904f   // 1/sqrt(2 ln2): exp(-d^2/2) = exp2(-(SCALE*d)^2)
#define SQRT2PI 2.5066282746310002f
#define KFP 0.46971863934f           // 1/(SCALE*sqrt(2pi)) : dPhiSum/dx = KFP*A
#define LN2 0.69314718056f

__device__ __forceinline__ uint64_t order_key(float f, int idx) {
  unsigned u = __float_as_uint(f);
  u = (u & 0x80000000u) ? ~u : (u | 0x80000000u);
  return ((uint64_t)u << 32) | (unsigned)idx;
}

__device__ __forceinline__ float e_of(const float* theta, const float* dur, int i) {
  return logf(dur[i] + 1e-32f) - theta[i];   // deterministic: identical everywhere
}

// grid geometry from the sorted endpoints (identical fp ops in every consumer)
__device__ __forceinline__ void grid_geom(const float2* xe, int n, float* x0, float* hx) {
  float a = xe[0].x - 7.0f;        // ~8 sigma margin in prescaled units
  float b = xe[n - 1].x + 7.0f;
  *x0 = a;
  *hx = (b - a) / (float)(GM - 1);
}

// ---------------------------------------------------------------------------
// Kernel 1: counting-rank partials (R2-proven, best measured rank: 512 blocks
// = 2 waves/SIMD so LDS/VALU latency is TLP-hidden, unlike the 1-block/CU
// register-rank variants of R8/R9). Block (ich, jch) owns IPT*RB i-keys and a
// JT-key j-tile in LDS; writes rank_part[jch*n + i] exactly once. Keys
// computed inline (3 logf/thread -- negligible vs the 1024-compare loop).
// One ds_read_b128 (2 j-keys) feeds 2*IPT = 4 comparisons.
// ---------------------------------------------------------------------------
__global__ __launch_bounds__(RB) void rank_part_kernel(
    const float* __restrict__ theta, const float* __restrict__ dur,
    int* __restrict__ rank_part, int n) {
  __shared__ ulonglong2 kt2[JT / 2];
  const int i0 = blockIdx.x * (RB * IPT) + threadIdx.x;
  const int i1 = i0 + RB;
  uint64_t ki0 = order_key(e_of(theta, dur, i0), i0);
  uint64_t ki1 = order_key(e_of(theta, dur, i1), i1);
  const int jbase = blockIdx.y * JT;
  {
    int j = jbase + threadIdx.x;          // JT == RB: one key per thread
    ((uint64_t*)kt2)[threadIdx.x] = order_key(e_of(theta, dur, j), j);
  }
  __syncthreads();
  int c0 = 0, c1 = 0;
  #pragma unroll 8
  for (int jj = 0; jj < JT / 2; ++jj) {
    ulonglong2 q = kt2[jj];               // LDS broadcast, 2 keys per read
    c0 += (q.x < ki0) ? 1 : 0;
    c1 += (q.x < ki1) ? 1 : 0;
    c0 += (q.y < ki0) ? 1 : 0;
    c1 += (q.y < ki1) ? 1 : 0;
  }
  rank_part[blockIdx.y * n + i0] = c0;
  rank_part[blockIdx.y * n + i1] = c1;
}

// ---------------------------------------------------------------------------
// Kernel 2: sum partials -> rank (== inverse permutation), then scatter into
// the interleaved (x, ev) array:
//   xe[rank[k]].x = SCALE*e[k]   (prescaled e_sorted, scatter - distinct dword)
//   xe[k].y       = ev[rank[k]]  (reference's inverse-perm side reorder)
//   th_s[k]       = theta[rank[k]]
// Also zeroes gbuf (4*GM = 4096 <= n) and out[0].
// ---------------------------------------------------------------------------
__global__ __launch_bounds__(RB) void scatter_kernel(
    const float* __restrict__ theta, const float* __restrict__ dur,
    const int* __restrict__ ev, const int* __restrict__ rank_part,
    float2* __restrict__ xe, float* __restrict__ th_s,
    float* __restrict__ gbuf, float* __restrict__ out, int n) {
  int k = blockIdx.x * RB + threadIdx.x;
  int r = 0;
  const int nj = n / JT;                 // 32
  #pragma unroll 32
  for (int jch = 0; jch < nj; ++jch) r += rank_part[jch * n + k];   // coalesced
  ((float*)&xe[r])[0] = SCALE * e_of(theta, dur, k);
  ((float*)&xe[k])[1] = (float)ev[r];
  th_s[k] = theta[r];
  if (k < 4 * GM) gbuf[k] = 0.0f;
  if (k == 0) out[0] = 0.0f;
}

// ---------------------------------------------------------------------------
// Kernel 3: Gauss transform on the grid. dp = x_m - x_j (prescaled).
//   A = sum g                    (pdf basis; FPhi' = KFP*A)
//   B = sum ev*g                 (condE numerator; B' = -2*ln2*D)
//   F = sum Phi(d)               (cdf-sum via 3-term erf reusing g)
//   D = sum dp*ev*g
// Spread atomics over 4096 distinct addresses pipeline fine (R2/R8-proven).
// ---------------------------------------------------------------------------
__global__ __launch_bounds__(RB) void gt_kernel(
    const float2* __restrict__ xe, float* __restrict__ gbuf, int n) {
  float x0, hx;
  grid_geom(xe, n, &x0, &hx);
  int m = blockIdx.x * RB + threadIdx.x;        // gridDim.x = GM/RB = 4
  float xm = fmaf((float)m, hx, x0);
  const int chunk = n / YS;                      // 64
  int jb = blockIdx.y * chunk;
  const float P2S = 0.39169197f;   // 0.47047*sqrt(ln2): t = 1/(1+p|d|/sqrt2)
  float a = 0.0f, b = 0.0f, f = 0.0f, d = 0.0f;
  #pragma unroll 8
  for (int jj = 0; jj < chunk; ++jj) {
    float2 q = xe[jb + jj];                      // block-uniform address
    float dp = xm - q.x;
    float g = __builtin_amdgcn_exp2f(-(dp * dp));  // exp(-d^2/2)
    float evg = q.y * g;
    a += g;
    b += evg;
    d = fmaf(dp, evg, d);
    // A&S 7.1.25 erf (p=0.47047, |err|<=2.5e-5), reuses g
    float tt = __builtin_amdgcn_rcpf(fmaf(P2S, __builtin_fabsf(dp), 1.0f));
    float poly = tt * (0.3480242f + tt * (-0.0958798f + tt * 0.7478556f));
    f += __builtin_copysignf(fmaf(-poly, g, 1.0f), dp);   // sign*erf
  }
  atomicAdd(&gbuf[m], a);
  atomicAdd(&gbuf[GM + m], b);
  atomicAdd(&gbuf[2 * GM + m], 0.5f * (float)chunk + 0.5f * f);  // Phi = .5+.5*s
  atomicAdd(&gbuf[3 * GM + m], d);
}

// ---------------------------------------------------------------------------
// Kernel 4: per-element cubic Hermite interpolation of FPhi (cdf-sum) and B
// (pdf*ev sum), then the loss terms. One atomic per block into zeroed out.
// ---------------------------------------------------------------------------
__global__ __launch_bounds__(RB) void final_kernel(
    const float2* __restrict__ xe, const float* __restrict__ th_s,
    const float* __restrict__ gbuf, float* __restrict__ out, int n) {
  float x0, hx;
  grid_geom(xe, n, &x0, &hx);
  const float* A = gbuf;
  const float* B = gbuf + GM;
  const float* F = gbuf + 2 * GM;
  const float* D = gbuf + 3 * GM;
  int i = blockIdx.x * RB + threadIdx.x;

  float term = 0.0f;
  if (i < n) {
    float2 q = xe[i];
    float u = (q.x - x0) * __builtin_amdgcn_rcpf(hx);
    int m = (int)u;
    m = min(max(m, 0), GM - 2);
    float t = u - (float)m;
    t = fminf(fmaxf(t, 0.0f), 1.0f);
    float t2 = t * t, t3 = t2 * t;
    float h00 = 2.0f * t3 - 3.0f * t2 + 1.0f;
    float h01 = 3.0f * t2 - 2.0f * t3;
    float h10 = t3 - 2.0f * t2 + t;
    float h11 = t3 - t2;
    float Fi = F[m] * h00 + F[m + 1] * h01 +
               hx * KFP * (A[m] * h10 + A[m + 1] * h11);
    float Bi = B[m] * h00 + B[m + 1] * h01 -
               2.0f * LN2 * hx * (D[m] * h10 + D[m + 1] * h11);
    const float fn = (float)n;
    float condE = fmaxf(Bi, 0.0f) * (1.0f / SQRT2PI) / fn + fn * 1e-32f;
    float surv = fmaxf(Fi, 0.25f) / fn;    // exact math gives Fi >= 0.5
    term = (__logf(condE) - __logf(surv) + th_s[i]) * q.y;
  }

  #pragma unroll
  for (int off = 32; off > 0; off >>= 1) term += __shfl_down(term, off, 64);
  __shared__ float red[RB / 64];
  int wave = threadIdx.x >> 6, lane = threadIdx.x & 63;
  if (lane == 0) red[wave] = term;
  __syncthreads();
  if (threadIdx.x == 0) {
    float s = 0.0f;
    #pragma unroll
    for (int w = 0; w < RB / 64; ++w) s += red[w];
    atomicAdd(out, -s / (float)n);
  }
}

extern "C" void kernel_launch(void* const* d_in, const int* in_sizes, int n_in,
                              void* d_out, int out_size, void* d_ws, size_t ws_size,
                              hipStream_t stream) {
  const float* theta = (const float*)d_in[0];   // log_h (n,1) fp32
  const float* dur   = (const float*)d_in[1];   // durations (n,) fp32
  const int*   ev    = (const int*)d_in[2];     // events (n,) int32
  float* out = (float*)d_out;
  const int n = in_sizes[1];

  // workspace layout (8-byte aligned first)
  char* ws = (char*)d_ws;
  float2* xe        = (float2*)ws;  ws += n * sizeof(float2);
  int*    rank_part = (int*)ws;     ws += (n / JT) * n * sizeof(int);
  float*  th_s      = (float*)ws;   ws += n * sizeof(float);
  float*  gbuf      = (float*)ws;   ws += 4 * GM * sizeof(float);  // A|B|F|D

  rank_part_kernel<<<dim3(n / (RB * IPT), n / JT), RB, 0, stream>>>(
      theta, dur, rank_part, n);
  scatter_kernel<<<n / RB, RB, 0, stream>>>(theta, dur, ev, rank_part,
                                            xe, th_s, gbuf, out, n);
  gt_kernel<<<dim3(GM / RB, YS), RB, 0, stream>>>(xe, gbuf, n);
  final_kernel<<<n / RB, RB, 0, stream>>>(xe, th_s, gbuf, out, n);
}